// Round 1
// baseline (1571.580 us; speedup 1.0000x reference)
//
#include <hip/hip_runtime.h>

#define NUM_GRAPHS 16384
#define EMB_DIM 128

// lower_bound over sorted int indices
__device__ __forceinline__ int lower_bound_i(const int* __restrict__ idx, int n, int val) {
    int lo = 0, hi = n;
    while (lo < hi) {
        int mid = (lo + hi) >> 1;
        if (idx[mid] < val) lo = mid + 1; else hi = mid;
    }
    return lo;
}

// One block per (graph, source) pair.
// blockIdx.x in [0, 16384)          -> atoms,  output cols [0,128)
// blockIdx.x in [16384, 32768)      -> frags,  output cols [128,256)
// 256 threads = 8 row-groups x 32 lanes; each lane owns one float4 column chunk.
__global__ __launch_bounds__(256) void segsum_concat_kernel(
    const float* __restrict__ x_atoms,
    const float* __restrict__ x_frags,
    const int*   __restrict__ batch,
    const int*   __restrict__ frag_batch,
    int n_atoms, int n_frags,
    float* __restrict__ out)
{
    const int b = blockIdx.x;
    int g, col_off, n;
    const float* x;
    const int* idx;
    if (b < NUM_GRAPHS) {
        g = b;              x = x_atoms; idx = batch;      n = n_atoms; col_off = 0;
    } else {
        g = b - NUM_GRAPHS; x = x_frags; idx = frag_batch; n = n_frags; col_off = EMB_DIM;
    }

    // uniform binary search for the contiguous row range of graph g
    const int start = lower_bound_i(idx, n, g);
    const int end   = lower_bound_i(idx, n, g + 1);

    const int tid  = threadIdx.x;
    const int col4 = tid & 31;   // float4 column chunk 0..31 (covers 128 floats)
    const int rg   = tid >> 5;   // row group 0..7

    const float4* __restrict__ xv = (const float4*)x;  // row stride = 32 float4

    float4 acc = make_float4(0.f, 0.f, 0.f, 0.f);
    for (int r = start + rg; r < end; r += 8) {
        float4 v = xv[(size_t)r * 32 + col4];
        acc.x += v.x; acc.y += v.y; acc.z += v.z; acc.w += v.w;
    }

    __shared__ float4 red[8][32];
    red[rg][col4] = acc;
    __syncthreads();

    if (tid < 32) {
        float4 s = red[0][col4];
        #pragma unroll
        for (int j = 1; j < 8; ++j) {
            float4 v = red[j][col4];
            s.x += v.x; s.y += v.y; s.z += v.z; s.w += v.w;
        }
        float4* __restrict__ outv = (float4*)(out + (size_t)g * (2 * EMB_DIM) + col_off);
        outv[col4] = s;
    }
}

extern "C" void kernel_launch(void* const* d_in, const int* in_sizes, int n_in,
                              void* d_out, int out_size, void* d_ws, size_t ws_size,
                              hipStream_t stream) {
    const float* x_atoms    = (const float*)d_in[0];
    const float* x_frags    = (const float*)d_in[1];
    const int*   batch      = (const int*)d_in[2];
    const int*   frag_batch = (const int*)d_in[3];
    float*       out        = (float*)d_out;

    const int n_atoms = in_sizes[2];
    const int n_frags = in_sizes[3];

    dim3 grid(2 * NUM_GRAPHS);
    dim3 block(256);
    segsum_concat_kernel<<<grid, block, 0, stream>>>(
        x_atoms, x_frags, batch, frag_batch, n_atoms, n_frags, out);
}